// Round 2
// baseline (1027.618 us; speedup 1.0000x reference)
//
#include <hip/hip_runtime.h>
#include <hip/hip_fp16.h>

#define FD 128            // feature dim
#define BSHIFT 9          // bucket = dst >> 9  (512 nodes per bucket)
#define BNODES 512
#define CAP 20480         // per-bucket capacity (avg 16.3K + >30 sigma)
#define SBLK 1024         // scatter blocks

typedef _Float16 half8 __attribute__((ext_vector_type(8)));
typedef float floatx4 __attribute__((ext_vector_type(4)));

// ---------------------------------------------------------------------------
// fp32 -> f16 conversion, dual layout: row-major [N][128] (gemm H operand)
// and chunked [4][N][32] (gather copy; 64 B per node-chunk = 1 cache line).
// ---------------------------------------------------------------------------
__global__ __launch_bounds__(256) void to_f16_kernel(const float4* __restrict__ in,
                                                     __half2* __restrict__ out,
                                                     __half2* __restrict__ outc,
                                                     int n4, int N) {
    int i = blockIdx.x * 256 + threadIdx.x;
    if (i < n4) {
        float4 v = in[i];
        __half2 h0 = __floats2half2_rn(v.x, v.y);
        __half2 h1 = __floats2half2_rn(v.z, v.w);
        out[2 * i + 0] = h0;
        out[2 * i + 1] = h1;
        size_t f0 = (size_t)i * 4;          // flat element index (multiple of 4)
        int row = (int)(f0 >> 7);
        int col = (int)(f0 & 127);
        int c = col >> 5;                   // feature chunk
        int j = col & 31;                   // position in chunk (multiple of 4)
        __half2* oc = outc + ((size_t)c * N + row) * 16 + (j >> 1);
        oc[0] = h0;
        oc[1] = h1;
    }
}

// ---------------------------------------------------------------------------
// Pack all 3 layers' [Wl;Wr] into MFMA B-frag order (one launch, 48 blocks).
// ---------------------------------------------------------------------------
__global__ __launch_bounds__(256) void pack_w3_kernel(const float* __restrict__ W1l,
                                                      const float* __restrict__ W1r,
                                                      const float* __restrict__ W2l,
                                                      const float* __restrict__ W2r,
                                                      const float* __restrict__ W3l,
                                                      const float* __restrict__ W3r,
                                                      half8* __restrict__ out) {
    int t = blockIdx.x * 256 + threadIdx.x;   // 0..12287
    int layer = t >> 12;
    int li = t & 4095;
    const float* Wl = (layer == 0) ? W1l : (layer == 1) ? W2l : W3l;
    const float* Wr = (layer == 0) ? W1r : (layer == 1) ? W2r : W3r;
    int lane = li & 63;
    int kt = (li >> 6) & 7;
    int nt = li >> 9;
    int n = nt * 16 + (lane & 15);
    int kq = kt * 32 + ((lane >> 4) & 3) * 8;
    half8 f;
#pragma unroll
    for (int j = 0; j < 8; ++j) {
        int k = kq + j;
        float v = (k < 128) ? Wl[n * 128 + k] : Wr[n * 128 + (k - 128)];
        f[j] = (_Float16)v;
    }
    out[t] = f;
}

// ---------------------------------------------------------------------------
// Bucketed scatter with block-level reservation. Entries packed into one int:
// (local_dst << 17) | src   (src < 2^17 since N = 100000; local_dst < 512).
// Halves sorted-buffer traffic vs int2.
// ---------------------------------------------------------------------------
__global__ __launch_bounds__(256) void scatter_kernel(const int* __restrict__ src,
                                                      const int* __restrict__ dst,
                                                      int* __restrict__ cursor,
                                                      int* __restrict__ sorted, int E) {
    __shared__ int cnt[256];
    __shared__ int base[256];
    int t = threadIdx.x;
    cnt[t] = 0;
    __syncthreads();
    int chunk = (E + SBLK - 1) / SBLK;
    int s0 = blockIdx.x * chunk;
    int s1 = s0 + chunk; if (s1 > E) s1 = E;
    for (int e = s0 + t; e < s1; e += 256)
        atomicAdd(&cnt[dst[e] >> BSHIFT], 1);
    __syncthreads();
    int c = cnt[t];
    if (c > 0) base[t] = atomicAdd(&cursor[t], c);
    cnt[t] = 0;
    __syncthreads();
    for (int e = s0 + t; e < s1; e += 256) {
        int d = dst[e];
        int b = d >> BSHIFT;
        int p = base[b] + atomicAdd(&cnt[b], 1);
        if (p < CAP) sorted[(size_t)b * CAP + p] = ((d & (BNODES - 1)) << 17) | src[e];
    }
}

// ---------------------------------------------------------------------------
// Per-bucket CSR build from packed entries.
// ---------------------------------------------------------------------------
__global__ __launch_bounds__(256) void bucket_build(const int* __restrict__ sorted,
                                                    const int* __restrict__ cursor,
                                                    int* __restrict__ row_ptr,
                                                    int* __restrict__ deg,
                                                    float* __restrict__ rdeg,
                                                    int* __restrict__ csr, int N) {
    __shared__ int dl[BNODES];
    __shared__ int ps[256];
    int b = blockIdx.x;
    int nbase = b << BSHIFT;
    int t = threadIdx.x;
    int cnt = cursor[b]; if (cnt > CAP) cnt = CAP;
    dl[t] = 0; dl[t + 256] = 0;
    __syncthreads();
    const int* se = sorted + (size_t)b * CAP;
    for (int e = t; e < cnt; e += 256)
        atomicAdd(&dl[((unsigned)se[e]) >> 17], 1);
    __syncthreads();
    int a0 = dl[2 * t], a1 = dl[2 * t + 1];
    ps[t] = a0 + a1;
    __syncthreads();
    for (int off = 1; off < 256; off <<= 1) {
        int v = (t >= off) ? ps[t - off] : 0;
        __syncthreads();
        ps[t] += v;
        __syncthreads();
    }
    int pre = ps[t] - a0 - a1;               // exclusive prefix of element 2t
    int cb = b * CAP;
    int n0 = nbase + 2 * t, n1 = n0 + 1;
    if (n0 < N) {
        row_ptr[n0] = cb + pre;
        deg[n0] = a0;
        rdeg[n0] = 1.0f / (float)(a0 > 1 ? a0 : 1);
    }
    if (n1 < N) {
        row_ptr[n1] = cb + pre + a0;
        deg[n1] = a1;
        rdeg[n1] = 1.0f / (float)(a1 > 1 ? a1 : 1);
    }
    dl[2 * t] = pre;
    dl[2 * t + 1] = pre + a0;
    __syncthreads();
    for (int e = t; e < cnt; e += 256) {
        int v = se[e];
        int p = atomicAdd(&dl[((unsigned)v) >> 17], 1);
        csr[cb + p] = v & 0x1FFFF;
    }
}

// ---------------------------------------------------------------------------
// Mean aggregation (R6, chunked gather): feature table in [4][N][32] f16
// chunks so each pass's random-gather working set is 6.4 MB (vs 25.6 MB) ->
// much higher L2 hit rate, less L2-fill traffic (the measured R5 wall).
// Per chunk: 16 dword-lanes cover the 64 B node-chunk, 4 edge slots per wave,
// 4 loads in flight; 2-level __shfl_xor reduce (same DS cost as R5).
// Output row-major aggB (gemm A operand). fp32 accumulate.
// ---------------------------------------------------------------------------
__global__ __launch_bounds__(256) void agg_kernel(const __half2* __restrict__ hc,
                                                  const int* __restrict__ row_ptr,
                                                  const int* __restrict__ deg,
                                                  const float* __restrict__ rdeg,
                                                  const int* __restrict__ csr,
                                                  __half2* __restrict__ out, int n) {
    int node = (blockIdx.x * 256 + threadIdx.x) >> 6;
    int lane = threadIdx.x & 63;
    if (node >= n) return;
    int slot = lane >> 4;       // edge slot 0..3
    int l16 = lane & 15;        // half2 within 64 B chunk
    int start = row_ptr[node];
    int d = deg[node];
    float r = rdeg[node];
    const size_t cstride = (size_t)n * 16;   // half2 units per chunk plane
#pragma unroll
    for (int c = 0; c < 4; ++c) {
        const __half2* base = hc + (size_t)c * cstride;
        float ax = 0.f, ay = 0.f;
        int i = 0;
        for (; i + 16 <= d; i += 16) {       // 4 gathers in flight / wave
            int s0 = csr[start + i + 0 + slot];
            int s1 = csr[start + i + 4 + slot];
            int s2 = csr[start + i + 8 + slot];
            int s3 = csr[start + i + 12 + slot];
            float2 v0 = __half22float2(base[(size_t)s0 * 16 + l16]);
            float2 v1 = __half22float2(base[(size_t)s1 * 16 + l16]);
            float2 v2 = __half22float2(base[(size_t)s2 * 16 + l16]);
            float2 v3 = __half22float2(base[(size_t)s3 * 16 + l16]);
            ax += v0.x; ay += v0.y;
            ax += v1.x; ay += v1.y;
            ax += v2.x; ay += v2.y;
            ax += v3.x; ay += v3.y;
        }
        for (; i + 4 <= d; i += 4) {
            int s = csr[start + i + slot];
            float2 v = __half22float2(base[(size_t)s * 16 + l16]);
            ax += v.x; ay += v.y;
        }
        if (i + slot < d) {                  // masked tail (d % 4)
            int s = csr[start + i + slot];
            float2 v = __half22float2(base[(size_t)s * 16 + l16]);
            ax += v.x; ay += v.y;
        }
        // reduce 4 edge slots (lane bits 4,5)
        ax += __shfl_xor(ax, 16, 64); ay += __shfl_xor(ay, 16, 64);
        ax += __shfl_xor(ax, 32, 64); ay += __shfl_xor(ay, 32, 64);
        if (slot == 0)
            out[(size_t)node * 64 + c * 16 + l16] = __floats2half2_rn(ax * r, ay * r);
    }
}

// ---------------------------------------------------------------------------
// MFMA GEMM: out = cat(A,H) @ Wcat^T + b (+ReLU). Row-major f16 in.
// f16 epilogue dual-writes row-major h (next gemm H operand) and chunked
// hc (next agg gather copy).
// ---------------------------------------------------------------------------
template <int OUT_FP32>
__global__ __launch_bounds__(256) void gemm_mfma(const __half* __restrict__ A,
                                                 const __half* __restrict__ H,
                                                 const half8* __restrict__ Wfrag,
                                                 const float* __restrict__ bias,
                                                 void* outp, __half* __restrict__ outc,
                                                 int n, int do_relu) {
    int tid = threadIdx.x;
    int wave = tid >> 6;
    int lane = tid & 63;
    int quad = (lane >> 4) & 3;
    int l16 = lane & 15;
    long tilebase = (long)blockIdx.x * 128;
    long r0 = tilebase + wave * 32 + l16;
    long r1 = r0 + 16;
    long ra = (r0 < n) ? r0 : (n - 1);
    long rb = (r1 < n) ? r1 : (n - 1);

    floatx4 acc[2][8];
#pragma unroll
    for (int m = 0; m < 2; ++m)
#pragma unroll
        for (int nt = 0; nt < 8; ++nt) acc[m][nt] = (floatx4){0.f, 0.f, 0.f, 0.f};

#pragma unroll
    for (int kt = 0; kt < 8; ++kt) {
        const __half* src = (kt < 4) ? A : H;
        int koff = (kt & 3) * 32 + quad * 8;
        half8 a0 = *(const half8*)(src + (size_t)ra * FD + koff);
        half8 a1 = *(const half8*)(src + (size_t)rb * FD + koff);
#pragma unroll
        for (int nt = 0; nt < 8; ++nt) {
            half8 b = Wfrag[(size_t)(nt * 8 + kt) * 64 + lane];
            acc[0][nt] = __builtin_amdgcn_mfma_f32_16x16x32_f16(a0, b, acc[0][nt], 0, 0, 0);
            acc[1][nt] = __builtin_amdgcn_mfma_f32_16x16x32_f16(a1, b, acc[1][nt], 0, 0, 0);
        }
    }

#pragma unroll
    for (int m = 0; m < 2; ++m) {
#pragma unroll
        for (int nt = 0; nt < 8; ++nt) {
            int col = nt * 16 + l16;
            float bv = bias[col];
#pragma unroll
            for (int r = 0; r < 4; ++r) {
                long row = tilebase + wave * 32 + m * 16 + quad * 4 + r;
                if (row < n) {
                    float v = acc[m][nt][r] + bv;
                    if (do_relu) v = v > 0.f ? v : 0.f;
                    if (OUT_FP32) {
                        ((float*)outp)[row * FD + col] = v;
                    } else {
                        __half hv = __float2half_rn(v);
                        ((__half*)outp)[row * FD + col] = hv;
                        // chunked copy: chunk = col>>5, pos = col&31
                        outc[((size_t)(nt >> 1) * n + row) * 32 + ((nt & 1) * 16 + l16)] = hv;
                    }
                }
            }
        }
    }
}

// ---------------------------------------------------------------------------
extern "C" void kernel_launch(void* const* d_in, const int* in_sizes, int n_in,
                              void* d_out, int out_size, void* d_ws, size_t ws_size,
                              hipStream_t stream) {
    const float* x   = (const float*)d_in[0];
    const int*   ei  = (const int*)d_in[1];
    const float* W1l = (const float*)d_in[2];
    const float* W1r = (const float*)d_in[3];
    const float* W2l = (const float*)d_in[4];
    const float* W2r = (const float*)d_in[5];
    const float* W3l = (const float*)d_in[6];
    const float* W3r = (const float*)d_in[7];
    const float* b1  = (const float*)d_in[8];
    const float* b2  = (const float*)d_in[9];
    const float* b3  = (const float*)d_in[10];
    float* out = (float*)d_out;

    int N = in_sizes[0] / FD;
    int E = in_sizes[1] / 2;
    const int* src = ei;
    const int* dst = ei + E;
    int B = (N + BNODES - 1) >> BSHIFT;   // 196 buckets

    char* ws = (char*)d_ws;
    size_t off = 0;
    auto alloc = [&](size_t bytes) -> void* {
        void* p = ws + off;
        off += (bytes + 255) & ~(size_t)255;
        return p;
    };
    int*    deg     = (int*)alloc((size_t)N * 4);
    int*    row_ptr = (int*)alloc((size_t)N * 4);
    float*  rdeg    = (float*)alloc((size_t)N * 4);
    int*    cursor  = (int*)alloc(256 * 4);
    int*    csr     = (int*)alloc((size_t)B * CAP * 4);
    __half* xb      = (__half*)alloc((size_t)N * FD * 2);
    __half* h1      = (__half*)alloc((size_t)N * FD * 2);
    __half* h2      = (__half*)alloc((size_t)N * FD * 2);
    __half* aggB    = (__half*)alloc((size_t)N * FD * 2);
    __half* xc      = (__half*)alloc((size_t)N * FD * 2);   // chunked copies
    __half* hc1     = (__half*)alloc((size_t)N * FD * 2);
    __half* hc2     = (__half*)alloc((size_t)N * FD * 2);
    half8*  wf      = (half8*)alloc((size_t)3 * 4096 * 16);
    int*    sorted  = (int*)alloc((size_t)B * CAP * 4);     // packed entries

    // ---- conversions / weight packing / CSR build ----
    int n4 = N * FD / 4;
    to_f16_kernel<<<(n4 + 255) / 256, 256, 0, stream>>>((const float4*)x, (__half2*)xb,
                                                        (__half2*)xc, n4, N);
    pack_w3_kernel<<<48, 256, 0, stream>>>(W1l, W1r, W2l, W2r, W3l, W3r, wf);
    hipMemsetAsync(cursor, 0, 256 * 4, stream);
    scatter_kernel<<<SBLK, 256, 0, stream>>>(src, dst, cursor, sorted, E);
    bucket_build<<<B, 256, 0, stream>>>(sorted, cursor, row_ptr, deg, rdeg, csr, N);

    int aggGrid  = (N + 3) / 4;
    int gemmGrid = (N + 127) / 128;

    // layer 1
    agg_kernel<<<aggGrid, 256, 0, stream>>>((const __half2*)xc, row_ptr, deg, rdeg, csr,
                                            (__half2*)aggB, N);
    gemm_mfma<0><<<gemmGrid, 256, 0, stream>>>(aggB, xb, wf, b1, h1, hc1, N, 1);
    // layer 2
    agg_kernel<<<aggGrid, 256, 0, stream>>>((const __half2*)hc1, row_ptr, deg, rdeg, csr,
                                            (__half2*)aggB, N);
    gemm_mfma<0><<<gemmGrid, 256, 0, stream>>>(aggB, h1, wf + 4096, b2, h2, hc2, N, 1);
    // layer 3 (no relu, fp32 out)
    agg_kernel<<<aggGrid, 256, 0, stream>>>((const __half2*)hc2, row_ptr, deg, rdeg, csr,
                                            (__half2*)aggB, N);
    gemm_mfma<1><<<gemmGrid, 256, 0, stream>>>(aggB, h2, wf + 8192, b3, out, nullptr, N, 0);
}